// Round 2
// baseline (78.468 us; speedup 1.0000x reference)
//
#include <hip/hip_runtime.h>
#include <math.h>

#define NN 768
#define DD 128

__device__ __forceinline__ double wred_d(double v) {
    #pragma unroll
    for (int o = 32; o > 0; o >>= 1) v += __shfl_down(v, o, 64);
    return v;
}
__device__ __forceinline__ float wred_f(float v) {
    #pragma unroll
    for (int o = 32; o > 0; o >>= 1) v += __shfl_down(v, o, 64);
    return v;
}

// One block per row i. Fully fused:
//   prologue: x2_i, sL_i = g0(||x_i||) * <x_i, w_l>
//   compact nonzero adj[i][:]
//   per neighbor j (one wave each): dot=<x_i,x_j>, y2=||x_j||^2, rd=<x_j,w_r>
//   scalar pair math (double): tangent_ij = common*(-alpha*x_i + beta*x_j)
//   aggregate u, then expmap/mobius_add/proj epilogue.
__global__ __launch_bounds__(256) void hypagg_fused(
        const float* __restrict__ x,
        const float* __restrict__ adj,
        const float* __restrict__ att_w,
        const float* __restrict__ att_b,
        float* __restrict__ out) {
    __shared__ float xi[DD];
    __shared__ float wr[DD];
    __shared__ int   list[NN];
    __shared__ float aval[NN];
    __shared__ float dots[NN];
    __shared__ float y2s[NN];
    __shared__ float rds[NN];
    __shared__ float bco[NN];
    __shared__ int   counter;
    __shared__ double pre[2][2];       // prologue partials: x2, <x,wl>
    __shared__ double s_x2i, s_beta, s_sLi, s_b0;
    __shared__ double cpart[4];        // asum partials
    __shared__ double epart[2][3];     // epilogue partials: un2, xu, on2

    const int i = blockIdx.x, t = threadIdx.x;
    const int wid = t >> 6, lane = t & 63;

    float xv = 0.0f;
    if (t < DD) {
        xv = x[i * DD + t];
        xi[t] = xv;
        wr[t] = att_w[DD + t];
        double dx2 = wred_d((double)xv * xv);
        double dwl = wred_d((double)xv * (double)att_w[t]);
        if (lane == 0) { pre[wid][0] = dx2; pre[wid][1] = dwl; }
    }
    if (t == 0) counter = 0;
    __syncthreads();

    if (t == 0) {
        double x2 = pre[0][0] + pre[1][0];
        double dl = pre[0][1] + pre[1][1];
        double r  = sqrt(x2);
        double g0 = atanh(fmin(r, 1.0 - 1e-7)) / fmax(r, 1e-15);
        s_x2i = x2;
        s_beta = 1.0 - x2;
        s_sLi = g0 * dl;
        s_b0  = (double)att_b[0];
    }

    // ---- compact nonzero columns of adj row i ----
    for (int j = t; j < NN; j += 256) {
        float a = adj[i * NN + j];
        if (a != 0.0f) {
            int k = atomicAdd(&counter, 1);
            list[k] = j;
            aval[k] = a;
        }
    }
    __syncthreads();
    const int n = counter;

    // ---- per-neighbor reductions: one wave per neighbor, 2 elems/lane ----
    for (int k = wid; k < n; k += 4) {
        const float* xj = x + (size_t)list[k] * DD;
        float a0 = xj[lane], a1 = xj[lane + 64];
        double dd = wred_d((double)xi[lane] * a0 + (double)xi[lane + 64] * a1);
        double dy = wred_d((double)a0 * a0 + (double)a1 * a1);
        float  dr = wred_f(wr[lane] * a0 + wr[lane + 64] * a1);
        if (lane == 0) { dots[k] = (float)dd; y2s[k] = (float)dy; rds[k] = dr; }
    }
    __syncthreads();

    // ---- scalar pair math (double) ----
    double asum = 0.0;
    {
        const double x2i = s_x2i, beta = s_beta, sLi = s_sLi, b0 = s_b0;
        const double factor = fmax(beta, 1e-15);   // 2/(sqrt_c*lambda_i)
        for (int k = t; k < n; k += 256) {
            double dot = (double)dots[k];
            double y2  = (double)y2s[k];
            double ry  = sqrt(y2);
            double g0j = atanh(fmin(ry, 1.0 - 1e-7)) / fmax(ry, 1e-15);
            double z   = sLi + g0j * (double)rds[k] + b0;
            double w   = (double)aval[k] / (1.0 + exp(-z));     // sigmoid * adj
            double alpha  = 1.0 - 2.0 * dot + y2;               // mobius_add(-x_i,x_j)
            double denomc = fmax(1.0 - 2.0 * dot + x2i * y2, 1e-15);
            double sn2 = (alpha * alpha * x2i - 2.0 * alpha * beta * dot + beta * beta * y2)
                         / (denomc * denomc);
            double sn  = fmax(sqrt(fmax(sn2, 0.0)), 1e-15);
            double g   = atanh(fmin(sn, 1.0 - 1e-7)) / sn;
            double common = w * factor * g / denomc;
            asum -= common * alpha;              // coefficient on x_i (row-summed)
            bco[k] = (float)(common * beta);     // coefficient on x_j
        }
    }
    asum = wred_d(asum);
    if (lane == 0) cpart[wid] = asum;
    __syncthreads();

    // ---- aggregate u = rowA*x_i + sum_k bco[k]*x_j  (t = dim) ----
    double u = 0.0;
    if (t < DD) {
        const double rowA = cpart[0] + cpart[1] + cpart[2] + cpart[3];
        u = rowA * (double)xv;
        for (int k = 0; k < n; ++k)
            u += (double)bco[k] * (double)x[(size_t)list[k] * DD + t];
        double p_un2 = wred_d(u * u);
        double p_xu  = wred_d((double)xv * u);
        if (lane == 0) { epart[wid][0] = p_un2; epart[wid][1] = p_xu; }
    }
    __syncthreads();

    // ---- expmap(u, x_i), mobius_add(x_i, second) ----
    double ov = 0.0;
    if (t < DD) {
        double un2 = epart[0][0] + epart[1][0];
        double xu  = epart[0][1] + epart[1][1];
        double lamfac = fmax(s_beta, 1e-15);            // 2/lambda_i
        double un = fmax(sqrt(un2), 1e-15);
        double th = tanh(un / lamfac);
        double s  = th / un;                            // second = s*u
        double y2 = s * s * un2;
        double xy = s * xu;
        double c1 = 1.0 + 2.0 * xy + y2;
        double c2 = 1.0 - s_x2i;
        double den = fmax(1.0 + 2.0 * xy + s_x2i * y2, 1e-15);
        ov = (c1 * (double)xv + c2 * s * u) / den;
        double p_on2 = wred_d(ov * ov);
        if (lane == 0) epart[wid][2] = p_on2;
    }
    __syncthreads();

    // ---- proj + store ----
    if (t < DD) {
        double on2 = epart[0][2] + epart[1][2];
        double on  = fmax(sqrt(on2), 1e-15);
        const double maxn = 1.0 - 4e-3;                 // (1-PROJ_EPS)/sqrt(c)
        double scale = (on > maxn) ? (maxn / on) : 1.0;
        out[i * DD + t] = (float)(ov * scale);
    }
}

extern "C" void kernel_launch(void* const* d_in, const int* in_sizes, int n_in,
                              void* d_out, int out_size, void* d_ws, size_t ws_size,
                              hipStream_t stream) {
    const float* x     = (const float*)d_in[0];
    const float* adj   = (const float*)d_in[1];
    const float* att_w = (const float*)d_in[2];
    const float* att_b = (const float*)d_in[3];
    float* out = (float*)d_out;
    hypagg_fused<<<NN, 256, 0, stream>>>(x, adj, att_w, att_b, out);
}

// Round 4
// 77.715 us; speedup vs baseline: 1.0097x; 1.0097x over previous
//
#include <hip/hip_runtime.h>
#include <math.h>

#define NN 768
#define DD 128
#define XC 64   // neighbor rows cached in LDS (binomial(768,0.04): mean~31, max~55)

__device__ __forceinline__ double wred_d(double v) {
    #pragma unroll
    for (int o = 32; o > 0; o >>= 1) v += __shfl_down(v, o, 64);
    return v;
}
__device__ __forceinline__ float wred_f(float v) {
    #pragma unroll
    for (int o = 32; o > 0; o >>= 1) v += __shfl_down(v, o, 64);
    return v;
}

// One block per row i. Double-precision scalar chains (mandatory: fp32-side
// noise pushes the knife-edge absmax over threshold — R3 evidence), float bulk
// data movement. Neighbor x_j rows cached in LDS between the dot phase and the
// aggregation phase.
__global__ __launch_bounds__(256) void hypagg_fused(
        const float* __restrict__ x,
        const float* __restrict__ adj,
        const float* __restrict__ att_w,
        const float* __restrict__ att_b,
        float* __restrict__ out) {
    __shared__ float xi[DD];
    __shared__ float wr[DD];
    __shared__ float xcache[XC][DD];   // 32 KB neighbor-row cache
    __shared__ int   list[NN];
    __shared__ float aval[NN];
    __shared__ float dots[NN];
    __shared__ float y2s[NN];
    __shared__ float rds[NN];
    __shared__ float bco[NN];
    __shared__ int   counter;
    __shared__ double pre[2][2];
    __shared__ double s_x2i, s_beta, s_sLi, s_b0;
    __shared__ double cpart[4];
    __shared__ double epart[2][3];

    const int i = blockIdx.x, t = threadIdx.x;
    const int wid = t >> 6, lane = t & 63;

    float xv = 0.0f;
    if (t < DD) {
        xv = x[i * DD + t];
        xi[t] = xv;
        wr[t] = att_w[DD + t];
        double dx2 = wred_d((double)xv * xv);
        double dwl = wred_d((double)xv * (double)att_w[t]);
        if (lane == 0) { pre[wid][0] = dx2; pre[wid][1] = dwl; }
    }
    if (t == 0) counter = 0;
    __syncthreads();

    if (t == 0) {
        double x2 = pre[0][0] + pre[1][0];
        double dl = pre[0][1] + pre[1][1];
        double r  = sqrt(x2);
        double g0 = atanh(fmin(r, 1.0 - 1e-7)) / fmax(r, 1e-15);
        s_x2i = x2;
        s_beta = 1.0 - x2;
        s_sLi = g0 * dl;
        s_b0  = (double)att_b[0];
    }

    // ---- compact nonzero columns of adj row i (float4 scan) ----
    if (t < NN / 4) {
        float4 a = ((const float4*)(adj + (size_t)i * NN))[t];
        int m = (a.x != 0.0f) + (a.y != 0.0f) + (a.z != 0.0f) + (a.w != 0.0f);
        if (m) {
            int base = atomicAdd(&counter, m);
            int j = 4 * t;
            if (a.x != 0.0f) { list[base] = j;     aval[base] = a.x; ++base; }
            if (a.y != 0.0f) { list[base] = j + 1; aval[base] = a.y; ++base; }
            if (a.z != 0.0f) { list[base] = j + 2; aval[base] = a.z; ++base; }
            if (a.w != 0.0f) { list[base] = j + 3; aval[base] = a.w; ++base; }
        }
    }
    __syncthreads();
    const int n = counter;

    // ---- per-neighbor reductions (one wave per neighbor) + LDS row cache ----
    const float2* xi2 = (const float2*)xi;
    const float2* wr2 = (const float2*)wr;
    for (int k = wid; k < n; k += 4) {
        const float2* xj2 = (const float2*)(x + (size_t)list[k] * DD);
        float2 a  = xj2[lane];
        if (k < XC) ((float2*)xcache[k])[lane] = a;
        float2 xw = xi2[lane];
        float2 ww = wr2[lane];
        double dd = wred_d((double)xw.x * a.x + (double)xw.y * a.y);
        double dy = wred_d((double)a.x * a.x + (double)a.y * a.y);
        float  dr = wred_f(ww.x * a.x + ww.y * a.y);
        if (lane == 0) { dots[k] = (float)dd; y2s[k] = (float)dy; rds[k] = dr; }
    }
    __syncthreads();

    // ---- scalar pair math (double) ----
    double asum = 0.0;
    {
        const double x2i = s_x2i, beta = s_beta, sLi = s_sLi, b0 = s_b0;
        const double factor = fmax(beta, 1e-15);   // 2/(sqrt_c*lambda_i)
        for (int k = t; k < n; k += 256) {
            double dot = (double)dots[k];
            double y2  = (double)y2s[k];
            double ry  = sqrt(y2);
            double g0j = atanh(fmin(ry, 1.0 - 1e-7)) / fmax(ry, 1e-15);
            double z   = sLi + g0j * (double)rds[k] + b0;
            double w   = (double)aval[k] / (1.0 + exp(-z));     // sigmoid * adj
            double alpha  = 1.0 - 2.0 * dot + y2;
            double denomc = fmax(1.0 - 2.0 * dot + x2i * y2, 1e-15);
            double sn2 = (alpha * alpha * x2i - 2.0 * alpha * beta * dot + beta * beta * y2)
                         / (denomc * denomc);
            double sn  = fmax(sqrt(fmax(sn2, 0.0)), 1e-15);
            double g   = atanh(fmin(sn, 1.0 - 1e-7)) / sn;
            double common = w * factor * g / denomc;
            asum -= common * alpha;              // coefficient on x_i (row-summed)
            bco[k] = (float)(common * beta);     // coefficient on x_j
        }
    }
    asum = wred_d(asum);
    if (lane == 0) cpart[wid] = asum;
    __syncthreads();

    // ---- aggregate u = rowA*x_i + sum_k bco[k]*x_j (LDS-cached rows) ----
    double u = 0.0;
    if (t < DD) {
        const double rowA = cpart[0] + cpart[1] + cpart[2] + cpart[3];
        u = rowA * (double)xv;
        const int nc = (n < XC) ? n : XC;
        for (int k = 0; k < nc; ++k)
            u += (double)bco[k] * (double)xcache[k][t];
        for (int k = XC; k < n; ++k)
            u += (double)bco[k] * (double)x[(size_t)list[k] * DD + t];
        double p_un2 = wred_d(u * u);
        double p_xu  = wred_d((double)xv * u);
        if (lane == 0) { epart[wid][0] = p_un2; epart[wid][1] = p_xu; }
    }
    __syncthreads();

    // ---- expmap(u, x_i), mobius_add(x_i, second) ----
    double ov = 0.0;
    if (t < DD) {
        double un2 = epart[0][0] + epart[1][0];
        double xu  = epart[0][1] + epart[1][1];
        double lamfac = fmax(s_beta, 1e-15);            // 2/lambda_i
        double un = fmax(sqrt(un2), 1e-15);
        double th = tanh(un / lamfac);
        double s  = th / un;                            // second = s*u
        double y2 = s * s * un2;
        double xy = s * xu;
        double c1 = 1.0 + 2.0 * xy + y2;
        double c2 = 1.0 - s_x2i;
        double den = fmax(1.0 + 2.0 * xy + s_x2i * y2, 1e-15);
        ov = (c1 * (double)xv + c2 * s * u) / den;
        double p_on2 = wred_d(ov * ov);
        if (lane == 0) epart[wid][2] = p_on2;
    }
    __syncthreads();

    // ---- proj + store ----
    if (t < DD) {
        double on2 = epart[0][2] + epart[1][2];
        double on  = fmax(sqrt(on2), 1e-15);
        const double maxn = 1.0 - 4e-3;                 // (1-PROJ_EPS)/sqrt(c)
        double scale = (on > maxn) ? (maxn / on) : 1.0;
        out[i * DD + t] = (float)(ov * scale);
    }
}

extern "C" void kernel_launch(void* const* d_in, const int* in_sizes, int n_in,
                              void* d_out, int out_size, void* d_ws, size_t ws_size,
                              hipStream_t stream) {
    const float* x     = (const float*)d_in[0];
    const float* adj   = (const float*)d_in[1];
    const float* att_w = (const float*)d_in[2];
    const float* att_b = (const float*)d_in[3];
    float* out = (float*)d_out;
    hypagg_fused<<<NN, 256, 0, stream>>>(x, adj, att_w, att_b, out);
}

// Round 5
// 71.843 us; speedup vs baseline: 1.0922x; 1.0817x over previous
//
#include <hip/hip_runtime.h>
#include <math.h>

#define NN 768
#define DD 128
#define XC 64   // neighbor rows cached in LDS (binomial(768,0.04): mean~31, max~55)

__device__ __forceinline__ double wred_d64(double v) {
    #pragma unroll
    for (int o = 32; o > 0; o >>= 1) v += __shfl_down(v, o, 64);
    return v;
}

// One block per row i. Double-precision scalar chains (mandatory: R3 showed
// fp32-side noise tips the knife-edge absmax over threshold), float bulk data
// movement, half-wave (width-32) parallel dot phase to shorten the serial
// critical path (4 rounds instead of 8 for the mean 31-neighbor row).
__global__ __launch_bounds__(256) void hypagg_fused(
        const float* __restrict__ x,
        const float* __restrict__ adj,
        const float* __restrict__ att_w,
        const float* __restrict__ att_b,
        float* __restrict__ out) {
    __shared__ float xi[DD];
    __shared__ float wr[DD];
    __shared__ float xcache[XC][DD];   // 32 KB neighbor-row cache
    __shared__ int   list[NN];
    __shared__ float aval[NN];
    __shared__ float dots[NN];
    __shared__ float y2s[NN];
    __shared__ float rds[NN];
    __shared__ float bco[NN];
    __shared__ int   counter;
    __shared__ double pre[2][2];
    __shared__ double s_x2i, s_beta, s_sLi, s_b0;
    __shared__ double cpart[4];
    __shared__ double epart[2][3];

    const int i = blockIdx.x, t = threadIdx.x;
    const int wid = t >> 6, lane = t & 63;

    float xv = 0.0f;
    if (t < DD) {
        xv = x[i * DD + t];
        xi[t] = xv;
        wr[t] = att_w[DD + t];
        double dx2 = wred_d64((double)xv * xv);
        double dwl = wred_d64((double)xv * (double)att_w[t]);
        if (lane == 0) { pre[wid][0] = dx2; pre[wid][1] = dwl; }
    }
    if (t == 0) counter = 0;
    __syncthreads();

    if (t == 0) {
        double x2 = pre[0][0] + pre[1][0];
        double dl = pre[0][1] + pre[1][1];
        double r  = sqrt(x2);
        double g0 = atanh(fmin(r, 1.0 - 1e-7)) / fmax(r, 1e-15);
        s_x2i = x2;
        s_beta = 1.0 - x2;
        s_sLi = g0 * dl;
        s_b0  = (double)att_b[0];
    }

    // ---- compact nonzero columns of adj row i (float4 scan) ----
    if (t < NN / 4) {
        float4 a = ((const float4*)(adj + (size_t)i * NN))[t];
        int m = (a.x != 0.0f) + (a.y != 0.0f) + (a.z != 0.0f) + (a.w != 0.0f);
        if (m) {
            int base = atomicAdd(&counter, m);
            int j = 4 * t;
            if (a.x != 0.0f) { list[base] = j;     aval[base] = a.x; ++base; }
            if (a.y != 0.0f) { list[base] = j + 1; aval[base] = a.y; ++base; }
            if (a.z != 0.0f) { list[base] = j + 2; aval[base] = a.z; ++base; }
            if (a.w != 0.0f) { list[base] = j + 3; aval[base] = a.w; ++base; }
        }
    }
    __syncthreads();
    const int n = counter;

    // ---- per-neighbor reductions: one HALF-WAVE (32 lanes, float4/lane) per
    //      neighbor; dot & y2 reduced in double (knife-edge consumers), rd float.
    {
        const int hw = t >> 5;   // half-wave id 0..7
        const int hl = t & 31;   // lane within half-wave
        const float4 xw = ((const float4*)xi)[hl];
        const float4 ww = ((const float4*)wr)[hl];
        for (int k = hw; k < n; k += 8) {
            float4 a = ((const float4*)(x + (size_t)list[k] * DD))[hl];
            if (k < XC) ((float4*)xcache[k])[hl] = a;
            double dd = (double)xw.x * a.x + (double)xw.y * a.y
                      + (double)xw.z * a.z + (double)xw.w * a.w;
            double dy = (double)a.x * a.x + (double)a.y * a.y
                      + (double)a.z * a.z + (double)a.w * a.w;
            float  dr = ww.x * a.x + ww.y * a.y + ww.z * a.z + ww.w * a.w;
            #pragma unroll
            for (int o = 16; o > 0; o >>= 1) {
                dd += __shfl_down(dd, o, 32);
                dy += __shfl_down(dy, o, 32);
                dr += __shfl_down(dr, o, 32);
            }
            if (hl == 0) { dots[k] = (float)dd; y2s[k] = (float)dy; rds[k] = dr; }
        }
    }
    __syncthreads();

    // ---- scalar pair math (double) ----
    double asum = 0.0;
    {
        const double x2i = s_x2i, beta = s_beta, sLi = s_sLi, b0 = s_b0;
        const double factor = fmax(beta, 1e-15);   // 2/(sqrt_c*lambda_i)
        for (int k = t; k < n; k += 256) {
            double dot = (double)dots[k];
            double y2  = (double)y2s[k];
            double ry  = sqrt(y2);
            double g0j = atanh(fmin(ry, 1.0 - 1e-7)) / fmax(ry, 1e-15);
            double z   = sLi + g0j * (double)rds[k] + b0;
            double w   = (double)aval[k] / (1.0 + exp(-z));     // sigmoid * adj
            double alpha  = 1.0 - 2.0 * dot + y2;
            double denomc = fmax(1.0 - 2.0 * dot + x2i * y2, 1e-15);
            double sn2 = (alpha * alpha * x2i - 2.0 * alpha * beta * dot + beta * beta * y2)
                         / (denomc * denomc);
            double sn  = fmax(sqrt(fmax(sn2, 0.0)), 1e-15);
            double g   = atanh(fmin(sn, 1.0 - 1e-7)) / sn;
            double common = w * factor * g / denomc;
            asum -= common * alpha;              // coefficient on x_i (row-summed)
            bco[k] = (float)(common * beta);     // coefficient on x_j
        }
    }
    asum = wred_d64(asum);
    if (lane == 0) cpart[wid] = asum;
    __syncthreads();

    // ---- aggregate u = rowA*x_i + sum_k bco[k]*x_j (LDS-cached rows) ----
    double u = 0.0;
    if (t < DD) {
        const double rowA = cpart[0] + cpart[1] + cpart[2] + cpart[3];
        u = rowA * (double)xv;
        const int nc = (n < XC) ? n : XC;
        for (int k = 0; k < nc; ++k)
            u += (double)bco[k] * (double)xcache[k][t];
        for (int k = XC; k < n; ++k)
            u += (double)bco[k] * (double)x[(size_t)list[k] * DD + t];
        double p_un2 = wred_d64(u * u);
        double p_xu  = wred_d64((double)xv * u);
        if (lane == 0) { epart[wid][0] = p_un2; epart[wid][1] = p_xu; }
    }
    __syncthreads();

    // ---- expmap(u, x_i), mobius_add(x_i, second) ----
    double ov = 0.0;
    if (t < DD) {
        double un2 = epart[0][0] + epart[1][0];
        double xu  = epart[0][1] + epart[1][1];
        double lamfac = fmax(s_beta, 1e-15);            // 2/lambda_i
        double un = fmax(sqrt(un2), 1e-15);
        double th = tanh(un / lamfac);
        double s  = th / un;                            // second = s*u
        double y2 = s * s * un2;
        double xy = s * xu;
        double c1 = 1.0 + 2.0 * xy + y2;
        double c2 = 1.0 - s_x2i;
        double den = fmax(1.0 + 2.0 * xy + s_x2i * y2, 1e-15);
        ov = (c1 * (double)xv + c2 * s * u) / den;
        double p_on2 = wred_d64(ov * ov);
        if (lane == 0) epart[wid][2] = p_on2;
    }
    __syncthreads();

    // ---- proj + store ----
    if (t < DD) {
        double on2 = epart[0][2] + epart[1][2];
        double on  = fmax(sqrt(on2), 1e-15);
        const double maxn = 1.0 - 4e-3;                 // (1-PROJ_EPS)/sqrt(c)
        double scale = (on > maxn) ? (maxn / on) : 1.0;
        out[i * DD + t] = (float)(ov * scale);
    }
}

extern "C" void kernel_launch(void* const* d_in, const int* in_sizes, int n_in,
                              void* d_out, int out_size, void* d_ws, size_t ws_size,
                              hipStream_t stream) {
    const float* x     = (const float*)d_in[0];
    const float* adj   = (const float*)d_in[1];
    const float* att_w = (const float*)d_in[2];
    const float* att_b = (const float*)d_in[3];
    float* out = (float*)d_out;
    hypagg_fused<<<NN, 256, 0, stream>>>(x, adj, att_w, att_b, out);
}

// Round 6
// 71.201 us; speedup vs baseline: 1.1021x; 1.0090x over previous
//
#include <hip/hip_runtime.h>
#include <math.h>

#define NN 768
#define DD 128
#define XC 64   // neighbor rows cached in LDS (binomial(768,0.04): mean~31, max~55)

// ---------------- K1: per-row scalars (double): x2, sL=g0*<x,wl>, sR=g0*<x,wr> ----------
__global__ __launch_bounds__(64) void row_kernel(
        const float* __restrict__ x, const float* __restrict__ att_w,
        double* __restrict__ x2a, double* __restrict__ sL, double* __restrict__ sR) {
    const int i = blockIdx.x, lane = threadIdx.x;   // one wave per row
    const float2 xv = ((const float2*)(x + (size_t)i * DD))[lane];
    const float2 wl = ((const float2*)att_w)[lane];
    const float2 wr = ((const float2*)(att_w + DD))[lane];
    double dx2 = (double)xv.x * xv.x + (double)xv.y * xv.y;
    double dl  = (double)xv.x * wl.x + (double)xv.y * wl.y;
    double dr  = (double)xv.x * wr.x + (double)xv.y * wr.y;
    #pragma unroll
    for (int o = 32; o > 0; o >>= 1) {
        dx2 += __shfl_down(dx2, o, 64);
        dl  += __shfl_down(dl,  o, 64);
        dr  += __shfl_down(dr,  o, 64);
    }
    if (lane == 0) {
        double r  = sqrt(dx2);
        double g0 = atanh(fmin(r, 1.0 - 1e-7)) / fmax(r, 1e-15);
        x2a[i] = dx2;
        sL[i]  = g0 * dl;
        sR[i]  = g0 * dr;
    }
}

// ---------------- K2: fused pair math + aggregation + expmap/proj ----------------------
__global__ __launch_bounds__(256) void hypagg_main(
        const float* __restrict__ x, const float* __restrict__ adj,
        const float* __restrict__ att_b,
        const double* __restrict__ x2a, const double* __restrict__ sL,
        const double* __restrict__ sR, float* __restrict__ out) {
    __shared__ float  xi[DD];
    __shared__ float  xcache[XC][DD];      // 32 KB neighbor-row cache
    __shared__ int    list[NN];
    __shared__ float  aval[NN];
    __shared__ double dots[NN];
    __shared__ float  bco[NN];
    __shared__ double upart[DD];           // odd-half aggregation partials
    __shared__ int    counter;
    __shared__ double s_x2i, s_sLi, s_b0;
    __shared__ double cpart[4];
    __shared__ double epart[2][3];

    const int i = blockIdx.x, t = threadIdx.x;
    const int wid = t >> 6, lane = t & 63;

    float xv = 0.0f;
    if (t < DD) { xv = x[i * DD + t]; xi[t] = xv; }
    if (t == 0) {
        counter = 0;
        s_x2i = x2a[i];
        s_sLi = sL[i];
        s_b0  = (double)att_b[0];
    }
    __syncthreads();

    // ---- compact nonzero columns of adj row i (float4 scan) ----
    if (t < NN / 4) {
        float4 a = ((const float4*)(adj + (size_t)i * NN))[t];
        int m = (a.x != 0.0f) + (a.y != 0.0f) + (a.z != 0.0f) + (a.w != 0.0f);
        if (m) {
            int base = atomicAdd(&counter, m);
            int j = 4 * t;
            if (a.x != 0.0f) { list[base] = j;     aval[base] = a.x; ++base; }
            if (a.y != 0.0f) { list[base] = j + 1; aval[base] = a.y; ++base; }
            if (a.z != 0.0f) { list[base] = j + 2; aval[base] = a.z; ++base; }
            if (a.w != 0.0f) { list[base] = j + 3; aval[base] = a.w; ++base; }
        }
    }
    __syncthreads();
    const int n = counter;

    // ---- dot phase: one 16-lane group per neighbor, 8 elems/lane, dot only ----
    {
        const int g  = t >> 4;     // group 0..15
        const int gl = t & 15;     // lane in group
        const float4 xa = ((const float4*)xi)[gl];
        const float4 xb = ((const float4*)xi)[16 + gl];
        for (int k = g; k < n; k += 16) {
            const float4* xj4 = (const float4*)(x + (size_t)list[k] * DD);
            float4 a = xj4[gl];        // elems gl*4 .. gl*4+3   (contiguous 256B/group)
            float4 b = xj4[16 + gl];   // elems 64+gl*4 ..       (next 256B)
            if (k < XC) {
                ((float4*)xcache[k])[gl]      = a;
                ((float4*)xcache[k])[16 + gl] = b;
            }
            double dd = (double)xa.x * a.x + (double)xa.y * a.y
                      + (double)xa.z * a.z + (double)xa.w * a.w
                      + (double)xb.x * b.x + (double)xb.y * b.y
                      + (double)xb.z * b.z + (double)xb.w * b.w;
            #pragma unroll
            for (int o = 8; o > 0; o >>= 1) dd += __shfl_down(dd, o, 16);
            if (gl == 0) dots[k] = dd;
        }
    }
    __syncthreads();

    // ---- scalar pair math (double); y2/sR are per-row, precomputed by K1 ----
    double asum = 0.0;
    {
        const double x2i = s_x2i, sLi = s_sLi, b0 = s_b0;
        const double beta = 1.0 - x2i;
        const double factor = fmax(beta, 1e-15);   // 2/(sqrt_c*lambda_i)
        for (int k = t; k < n; k += 256) {
            const int j = list[k];
            double dot = dots[k];
            double y2  = x2a[j];
            double z   = sLi + sR[j] + b0;
            double w   = (double)aval[k] / (1.0 + exp(-z));     // sigmoid * adj
            double alpha  = 1.0 - 2.0 * dot + y2;
            double denomc = fmax(1.0 - 2.0 * dot + x2i * y2, 1e-15);
            double sn2 = (alpha * alpha * x2i - 2.0 * alpha * beta * dot + beta * beta * y2)
                         / (denomc * denomc);
            double sn  = fmax(sqrt(fmax(sn2, 0.0)), 1e-15);
            double g   = atanh(fmin(sn, 1.0 - 1e-7)) / sn;
            double common = w * factor * g / denomc;
            asum -= common * alpha;              // coefficient on x_i (row-summed)
            bco[k] = (float)(common * beta);     // coefficient on x_j
        }
    }
    #pragma unroll
    for (int o = 32; o > 0; o >>= 1) asum += __shfl_down(asum, o, 64);
    if (lane == 0) cpart[wid] = asum;
    __syncthreads();

    // ---- aggregation: even k on t<128, odd k on t>=128, combine via LDS ----
    {
        const int d = t & (DD - 1);
        const int h = t >> 7;              // 0: even ks + final, 1: odd ks
        double p = 0.0;
        const int nc = (n < XC) ? n : XC;
        for (int k = h; k < nc; k += 2) p += (double)bco[k] * (double)xcache[k][d];
        for (int k = XC + h; k < n; k += 2) p += (double)bco[k] * (double)x[(size_t)list[k] * DD + d];
        if (h == 1) upart[d] = p;
        __syncthreads();
        if (t < DD) {
            const double rowA = cpart[0] + cpart[1] + cpart[2] + cpart[3];
            double u = rowA * (double)xv + p + upart[d];
            double p_un2 = u * u;
            double p_xu  = (double)xv * u;
            #pragma unroll
            for (int o = 32; o > 0; o >>= 1) {
                p_un2 += __shfl_down(p_un2, o, 64);
                p_xu  += __shfl_down(p_xu,  o, 64);
            }
            if (lane == 0) { epart[wid][0] = p_un2; epart[wid][1] = p_xu; }
            upart[d] = u;   // reuse as u-store for epilogue (after the reduce)
        }
    }
    __syncthreads();

    // ---- expmap(u, x_i), mobius_add(x_i, second) ----
    double ov = 0.0;
    if (t < DD) {
        double u   = upart[t];
        double un2 = epart[0][0] + epart[1][0];
        double xu  = epart[0][1] + epart[1][1];
        double x2i = s_x2i;
        double lamfac = fmax(1.0 - x2i, 1e-15);         // 2/lambda_i
        double un = fmax(sqrt(un2), 1e-15);
        double th = tanh(un / lamfac);
        double s  = th / un;                            // second = s*u
        double y2 = s * s * un2;
        double xy = s * xu;
        double c1 = 1.0 + 2.0 * xy + y2;
        double c2 = 1.0 - x2i;
        double den = fmax(1.0 + 2.0 * xy + x2i * y2, 1e-15);
        ov = (c1 * (double)xv + c2 * s * u) / den;
        double p_on2 = ov * ov;
        #pragma unroll
        for (int o = 32; o > 0; o >>= 1) p_on2 += __shfl_down(p_on2, o, 64);
        if (lane == 0) epart[wid][2] = p_on2;
    }
    __syncthreads();

    // ---- proj + store ----
    if (t < DD) {
        double on2 = epart[0][2] + epart[1][2];
        double on  = fmax(sqrt(on2), 1e-15);
        const double maxn = 1.0 - 4e-3;                 // (1-PROJ_EPS)/sqrt(c)
        double scale = (on > maxn) ? (maxn / on) : 1.0;
        out[i * DD + t] = (float)(ov * scale);
    }
}

extern "C" void kernel_launch(void* const* d_in, const int* in_sizes, int n_in,
                              void* d_out, int out_size, void* d_ws, size_t ws_size,
                              hipStream_t stream) {
    const float* x     = (const float*)d_in[0];
    const float* adj   = (const float*)d_in[1];
    const float* att_w = (const float*)d_in[2];
    const float* att_b = (const float*)d_in[3];
    float* out = (float*)d_out;

    double* x2a = (double*)d_ws;        // 768 doubles
    double* sL  = x2a + NN;             // 768 doubles
    double* sR  = sL + NN;              // 768 doubles

    row_kernel<<<NN, 64, 0, stream>>>(x, att_w, x2a, sL, sR);
    hypagg_main<<<NN, 256, 0, stream>>>(x, adj, att_b, x2a, sL, sR, out);
}